// Round 6
// baseline (122.095 us; speedup 1.0000x reference)
//
#include <hip/hip_runtime.h>

#define N_NODES 2048
#define F_IN    2048
#define G1      10
#define NCLS    10
#define NEDGE   65536
#define JC      8           // split-K chunks over F_IN
#define JPER    256         // K elems per chunk (JC*JPER = F_IN)
#define ROWS    64          // rows per GEMM block tile
#define ZS      64          // scatter slices per k-half

// g_y / g_deg are accumulated by device-scope atomics in K1; they are
// pre-zeroed by the PREVIOUS call's K3 (bss is zero at module load; this
// atomics-after-plain-store-across-launch pattern was validated in round 4
// over all verify+profile iterations). g_zp is fully overwritten each call.
__device__ float g_y[N_NODES * 20];             // [row][k]: k<10 x@W0, k>=10 x@W1
__device__ int   g_deg[N_NODES];                // degree histogram
__device__ float g_zp[2 * ZS * N_NODES * 5];    // scatter partials (5.25 MB)

// ---- K1: split-K GEMM x@[W0|W1] -> atomic g_y ; degree hist -> atomic g_deg ----
// 256 blocks = 8 K-chunks x 32 row-tiles. 256 threads = 4 wave-groups:
// kg = {W0|W1} x {k 0..4 | k 5..9}, 64 rows each. W rows loop-uniform -> s_load.
__global__ __launch_bounds__(256) void k_gemm(const float* __restrict__ x,
                                              const float* __restrict__ W0,
                                              const float* __restrict__ W1,
                                              const int* __restrict__ ei) {
    __shared__ __align__(16) float smem[ROWS * 257];   // 64x256 tile, stride 257
    const int tid = threadIdx.x;
    const int bx  = blockIdx.x;
    int jc   = bx & (JC - 1);          // 0..7
    int rb   = bx >> 3;                // 0..31
    int j0   = jc * JPER;
    int row0 = rb * ROWS;

    #pragma unroll
    for (int rep = 0; rep < 16; ++rep) {
        int idx = rep * 256 + tid;
        int r = idx >> 6, c4 = idx & 63;
        float4 v = *(const float4*)(x + (size_t)(row0 + r) * F_IN + j0 + c4 * 4);
        float* d = smem + r * 257 + c4 * 4;
        d[0] = v.x; d[1] = v.y; d[2] = v.z; d[3] = v.w;
    }
    // fused degree histogram: 256 edges per block (g_deg pre-zeroed)
    atomicAdd(&g_deg[ei[bx * 256 + tid]], 1);
    __syncthreads();

    int ri   = tid & (ROWS - 1);       // row within tile
    int kg   = tid >> 6;               // wave index 0..3 (wave-uniform)
    int mat  = kg >> 1;                // 0 -> W0, 1 -> W1
    int half = kg & 1;                 // output cols [half*5, half*5+5)
    const float* Wm = mat ? W1 : W0;
    float acc[5] = {0.f, 0.f, 0.f, 0.f, 0.f};
    const float* xr = smem + ri * 257;
    #pragma unroll 8
    for (int j = 0; j < JPER; ++j) {
        float xu = xr[j];
        const float* wr = Wm + (size_t)(j0 + j) * G1 + half * 5;  // uniform
        #pragma unroll
        for (int k = 0; k < 5; ++k) acc[k] += xu * wr[k];
    }
    int row = row0 + ri;
    #pragma unroll
    for (int k = 0; k < 5; ++k)
        atomicAdd(&g_y[row * 20 + mat * 10 + half * 5 + k], acc[k]);  // 8/elem
}

// ---- K2: edge scatter in projected space, LDS-privatized -> g_zp ----
__global__ __launch_bounds__(256) void k_scatter(const int* __restrict__ ei) {
    __shared__ float zl[N_NODES * 5];            // 40 KB
    int khalf  = blockIdx.x >> 6;
    int bslice = blockIdx.x & (ZS - 1);
    float4* zl4 = (float4*)zl;
    #pragma unroll
    for (int t = threadIdx.x; t < N_NODES * 5 / 4; t += 256)
        zl4[t] = make_float4(0.f, 0.f, 0.f, 0.f);
    __syncthreads();
    int base = bslice * (NEDGE / ZS);            // 1024 edges
    #pragma unroll
    for (int u = 0; u < NEDGE / ZS / 256; ++u) {
        int e = base + u * 256 + threadIdx.x;
        int r = ei[e], c = ei[NEDGE + e];
        int dr = g_deg[r], dc = g_deg[c];
        float w = -(dr > 0 ? rsqrtf((float)dr) : 0.f) *
                   (dc > 0 ? rsqrtf((float)dc) : 0.f);
        const float* y1 = g_y + r * 20 + 10 + khalf * 5;
        float* zz = zl + c * 5;
        #pragma unroll
        for (int kk = 0; kk < 5; ++kk) atomicAdd(&zz[kk], w * y1[kk]);
    }
    __syncthreads();
    float4* dst = (float4*)(g_zp + ((size_t)khalf * ZS + bslice) * (N_NODES * 5));
    #pragma unroll
    for (int t = threadIdx.x; t < N_NODES * 5 / 4; t += 256) dst[t] = zl4[t];
}

// ---- K3: z-reduce + epilogue + re-zero accumulators for the next call ----
// 64 blocks x 320 threads: thread t = (node i = t/10, channel k = t%10).
__global__ __launch_bounds__(320) void k_final(const float* __restrict__ b,
                                               const float* __restrict__ Wf,
                                               const float* __restrict__ bfv,
                                               float* __restrict__ out) {
    __shared__ float sh[320];
    int tid = threadIdx.x;
    int t = blockIdx.x * 320 + tid;              // t < 20480
    int i = t / 10, k = t - i * 10;
    int khalf = k / 5, kk = k - khalf * 5;
    float s = 0.f;
    #pragma unroll 16
    for (int sl = 0; sl < ZS; ++sl)
        s += g_zp[((size_t)khalf * ZS + sl) * (N_NODES * 5) + i * 5 + kk];
    sh[tid] = fmaxf(g_y[i * 20 + k] + s + b[k], 0.f);
    // re-zero for next call: this thread owns (i,k) and (i,k+10); y1 is
    // never read in K3, y0 only by this thread (already in sh).
    g_y[i * 20 + k]      = 0.f;
    g_y[i * 20 + 10 + k] = 0.f;
    if (t < N_NODES) g_deg[t] = 0;
    __syncthreads();
    if (tid < 32) {
        int node = blockIdx.x * 32 + tid;
        const float* h = sh + tid * 10;
        float lo[NCLS];
        #pragma unroll
        for (int c = 0; c < NCLS; ++c) lo[c] = bfv[c];
        #pragma unroll
        for (int kq = 0; kq < G1; ++kq) {
            float hk = h[kq];
            #pragma unroll
            for (int c = 0; c < NCLS; ++c) lo[c] += hk * Wf[kq * NCLS + c];
        }
        float m = lo[0];
        #pragma unroll
        for (int c = 1; c < NCLS; ++c) m = fmaxf(m, lo[c]);
        float sum = 0.f;
        #pragma unroll
        for (int c = 0; c < NCLS; ++c) sum += expf(lo[c] - m);
        float ls = logf(sum);
        #pragma unroll
        for (int c = 0; c < NCLS; ++c) out[node * NCLS + c] = lo[c] - m - ls;
    }
}

extern "C" void kernel_launch(void* const* d_in, const int* in_sizes, int n_in,
                              void* d_out, int out_size, void* d_ws, size_t ws_size,
                              hipStream_t stream) {
    const float* x   = (const float*)d_in[0];
    const int*   ei  = (const int*)d_in[1];
    const float* W0  = (const float*)d_in[2];
    const float* W1  = (const float*)d_in[3];
    const float* b   = (const float*)d_in[4];
    const float* Wf  = (const float*)d_in[5];
    const float* bfv = (const float*)d_in[6];
    float* out = (float*)d_out;

    k_gemm<<<dim3(JC * (N_NODES / ROWS)), 256, 0, stream>>>(x, W0, W1, ei);
    k_scatter<<<2 * ZS, 256, 0, stream>>>(ei);
    k_final<<<N_NODES / 32, 320, 0, stream>>>(b, Wf, bfv, out);
}